// Round 5
// baseline (12777.761 us; speedup 1.0000x reference)
//
#include <hip/hip_runtime.h>
#include <hip/hip_bf16.h>

#define T_STEPS 256
#define BATCH   128
#define IDIM    512
#define HDIM    1024
#define NLAYERS 4
#define G3      (3 * HDIM)
#define BH      (BATCH * HDIM)   // 131072 elements
#define CHUNK   16               // wavefront chunk (timesteps)
#define RING    (2 * CHUNK)      // inter-layer ring depth (slots)

typedef __bf16 bf16_t;
typedef __bf16 bf16x4 __attribute__((ext_vector_type(4)));
typedef __bf16 bf16x8 __attribute__((ext_vector_type(8)));
typedef float  f32x4  __attribute__((ext_vector_type(4)));

__device__ __forceinline__ float sigm_f(float x) { return 1.0f / (1.0f + __expf(-x)); }
__device__ __forceinline__ float tanh_f(float x) { return 1.0f - 2.0f / (__expf(2.0f * x) + 1.0f); }

// fp32 -> bf16, 4 elements per thread. n4 = n/4.
__global__ void cvt_f2b(const float* __restrict__ s, bf16_t* __restrict__ d, int n4) {
    int i = blockIdx.x * blockDim.x + threadIdx.x;
    if (i < n4) {
        f32x4 v = ((const f32x4*)s)[i];
        bf16x4 o;
        o[0] = (bf16_t)v[0]; o[1] = (bf16_t)v[1];
        o[2] = (bf16_t)v[2]; o[3] = (bf16_t)v[3];
        ((bf16x4*)d)[i] = o;
    }
}

// fp32 h -> bf16 hi/lo split, 4 per thread over BH elements.
__global__ void split_h(const float* __restrict__ s,
                        bf16_t* __restrict__ hi, bf16_t* __restrict__ lo) {
    int i = blockIdx.x * blockDim.x + threadIdx.x;  // < BH/4
    f32x4 v = ((const f32x4*)s)[i];
    bf16x4 h, l;
#pragma unroll
    for (int j = 0; j < 4; ++j) {
        bf16_t t = (bf16_t)v[j];
        h[j] = t;
        l[j] = (bf16_t)(v[j] - (float)t);
    }
    ((bf16x4*)hi)[i] = h;
    ((bf16x4*)lo)[i] = l;
}

// Per-active-layer parameters for one fused timestep.
struct LayerStep {
    const bf16_t* inp;       // (B, kin) bf16 input slice for this t
    const bf16_t* w_ih;      // (3H, kin) bf16
    const bf16_t* w_hh;      // (3H, H) bf16
    const float*  b_ih;      // (3H) fp32
    const float*  b_hh;      // (3H) fp32
    const bf16_t* h_in_hi;
    const bf16_t* h_in_lo;
    bf16_t*       h_out_hi;
    bf16_t*       h_out_lo;
    bf16_t*       y_bf;      // (B, H) bf16 ring slot, or nullptr (last layer)
    float*        y_f32;     // (B, H) fp32 ys slice, or nullptr (layers 0..2)
    float*        h_final;   // (B, H) fp32 or nullptr
    int           t;
    int           kin;       // 512 (layer 0) or 1024
};
struct StepArgs { LayerStep L[NLAYERS]; };

// Phase B v4: one full GRU timestep (input + hidden projection + gates) for
// up to 4 independent (layer, chunk) pairs. Grid (64 col-groups of 16,
// 2 batch-groups of 64, n_active) x 512 threads (8 waves = 4 K-quarters x
// 2 row-halves). vs v3: col-tile halved 32->16 so each wave holds 8 accs,
// LDS reduce is 64 KB, and 512 blocks run 2/CU (4 waves/SIMD) for latency
// hiding — the kernel was memory-latency bound at 2 waves/SIMD. Per-output
// summation order (K-quartering, hi-then-lo, kq tree) is identical to v3.
__global__ __launch_bounds__(512, 4)
void gru_step_multi(StepArgs args, const int* __restrict__ lengths)
{
    __shared__ f32x4 red[4][4][2][2][64];  // [kq][kind][rh][rf][lane] 64KB
                                           // kind: 0=r, 1=z, 2=hn, 3=in

    const LayerStep& A = args.L[blockIdx.z];

    const int tid  = threadIdx.x;
    const int wid  = tid >> 6;        // 0..7
    const int lane = tid & 63;
    const int cq   = lane & 15;
    const int quad = lane >> 4;
    const int c0   = blockIdx.x * 16; // hidden col group
    const int m0   = blockIdx.y * 64; // batch group

    // K-loop role: kq = K-quarter, rh = row half (32 rows).
    const int kq = wid & 3;
    const int rh = wid >> 2;

    f32x4 arz[2][2];   // [rf][gate r/z]  (input + hidden combined)
    f32x4 ahn[2];      // [rf] hidden n
    f32x4 ain[2];      // [rf] input n
#pragma unroll
    for (int rf = 0; rf < 2; ++rf) {
        arz[rf][0] = f32x4{0, 0, 0, 0};
        arz[rf][1] = f32x4{0, 0, 0, 0};
        ahn[rf]    = f32x4{0, 0, 0, 0};
        ain[rf]    = f32x4{0, 0, 0, 0};
    }

    // ---- Hidden projection: K = 1024 (quarter 256), hi then lo ----
    {
        const int kofs = kq * 256 + quad * 8;
        const bf16_t* aph0 = A.h_in_hi + (size_t)(m0 + rh * 32 + cq) * HDIM + kofs;
        const bf16_t* aph1 = aph0 + (size_t)16 * HDIM;
        const bf16_t* apl0 = A.h_in_lo + (size_t)(m0 + rh * 32 + cq) * HDIM + kofs;
        const bf16_t* apl1 = apl0 + (size_t)16 * HDIM;
        const bf16_t* bp0 = A.w_hh + (size_t)(0 * HDIM + c0 + cq) * HDIM + kofs;
        const bf16_t* bp1 = A.w_hh + (size_t)(1 * HDIM + c0 + cq) * HDIM + kofs;
        const bf16_t* bp2 = A.w_hh + (size_t)(2 * HDIM + c0 + cq) * HDIM + kofs;

#pragma unroll
        for (int k = 0; k < 256; k += 32) {
            bf16x8 Ah[2], Al[2], Bv[3];
            Ah[0] = *(const bf16x8*)(aph0 + k);
            Ah[1] = *(const bf16x8*)(aph1 + k);
            Al[0] = *(const bf16x8*)(apl0 + k);
            Al[1] = *(const bf16x8*)(apl1 + k);
            Bv[0] = *(const bf16x8*)(bp0 + k);
            Bv[1] = *(const bf16x8*)(bp1 + k);
            Bv[2] = *(const bf16x8*)(bp2 + k);
            // hi first, then lo (per-acc order identical to v3)
#pragma unroll
            for (int rf = 0; rf < 2; ++rf) {
                arz[rf][0] = __builtin_amdgcn_mfma_f32_16x16x32_bf16(
                    Ah[rf], Bv[0], arz[rf][0], 0, 0, 0);
                arz[rf][1] = __builtin_amdgcn_mfma_f32_16x16x32_bf16(
                    Ah[rf], Bv[1], arz[rf][1], 0, 0, 0);
                ahn[rf] = __builtin_amdgcn_mfma_f32_16x16x32_bf16(
                    Ah[rf], Bv[2], ahn[rf], 0, 0, 0);
            }
#pragma unroll
            for (int rf = 0; rf < 2; ++rf) {
                arz[rf][0] = __builtin_amdgcn_mfma_f32_16x16x32_bf16(
                    Al[rf], Bv[0], arz[rf][0], 0, 0, 0);
                arz[rf][1] = __builtin_amdgcn_mfma_f32_16x16x32_bf16(
                    Al[rf], Bv[1], arz[rf][1], 0, 0, 0);
                ahn[rf] = __builtin_amdgcn_mfma_f32_16x16x32_bf16(
                    Al[rf], Bv[2], ahn[rf], 0, 0, 0);
            }
        }
    }

    // ---- Input projection: K = kin (quarter kin/4), single bf16 pass ----
    {
        const int kin  = A.kin;
        const int qw   = kin >> 2;            // 256 or 128
        const int kofs = kq * qw + quad * 8;
        const bf16_t* axp0 = A.inp + (size_t)(m0 + rh * 32 + cq) * kin + kofs;
        const bf16_t* axp1 = axp0 + (size_t)16 * kin;
        const bf16_t* wp0 = A.w_ih + (size_t)(0 * HDIM + c0 + cq) * kin + kofs;
        const bf16_t* wp1 = A.w_ih + (size_t)(1 * HDIM + c0 + cq) * kin + kofs;
        const bf16_t* wp2 = A.w_ih + (size_t)(2 * HDIM + c0 + cq) * kin + kofs;

#pragma unroll 4
        for (int k = 0; k < qw; k += 32) {
            bf16x8 Ax[2], Wv[3];
            Ax[0] = *(const bf16x8*)(axp0 + k);
            Ax[1] = *(const bf16x8*)(axp1 + k);
            Wv[0] = *(const bf16x8*)(wp0 + k);
            Wv[1] = *(const bf16x8*)(wp1 + k);
            Wv[2] = *(const bf16x8*)(wp2 + k);
#pragma unroll
            for (int rf = 0; rf < 2; ++rf) {
                arz[rf][0] = __builtin_amdgcn_mfma_f32_16x16x32_bf16(
                    Ax[rf], Wv[0], arz[rf][0], 0, 0, 0);
                arz[rf][1] = __builtin_amdgcn_mfma_f32_16x16x32_bf16(
                    Ax[rf], Wv[1], arz[rf][1], 0, 0, 0);
                ain[rf] = __builtin_amdgcn_mfma_f32_16x16x32_bf16(
                    Ax[rf], Wv[2], ain[rf], 0, 0, 0);
            }
        }
    }

#pragma unroll
    for (int rf = 0; rf < 2; ++rf) {
        red[kq][0][rh][rf][lane] = arz[rf][0];
        red[kq][1][rh][rf][lane] = arz[rf][1];
        red[kq][2][rh][rf][lane] = ahn[rf];
        red[kq][3][rh][rf][lane] = ain[rf];
    }
    __syncthreads();

    // Gate phase: 4 output subtiles (grh, grf); two waves split each
    // subtile's 4 acc-rows (ihalf). Per-element op order identical to v3.
    {
        const int grh   = wid & 1;
        const int grf   = (wid >> 1) & 1;
        const int ihalf = wid >> 2;   // 0..1
        const int col   = c0 + cq;

        f32x4 sr = ((red[0][0][grh][grf][lane] + red[1][0][grh][grf][lane])
                  +  red[2][0][grh][grf][lane]) + red[3][0][grh][grf][lane];
        f32x4 sz = ((red[0][1][grh][grf][lane] + red[1][1][grh][grf][lane])
                  +  red[2][1][grh][grf][lane]) + red[3][1][grh][grf][lane];
        f32x4 shn = ((red[0][2][grh][grf][lane] + red[1][2][grh][grf][lane])
                   +  red[2][2][grh][grf][lane]) + red[3][2][grh][grf][lane];
        f32x4 sin_ = ((red[0][3][grh][grf][lane] + red[1][3][grh][grf][lane])
                    +  red[2][3][grh][grf][lane]) + red[3][3][grh][grf][lane];

        const float bir = A.b_ih[col];
        const float biz = A.b_ih[HDIM + col];
        const float bin = A.b_ih[2 * HDIM + col];
        const float bhr = A.b_hh[col];
        const float bhz = A.b_hh[HDIM + col];
        const float bhn = A.b_hh[2 * HDIM + col];

#pragma unroll
        for (int j = 0; j < 2; ++j) {
            const int i   = ihalf * 2 + j;
            const int row = m0 + grh * 32 + grf * 16 + quad * 4 + i;  // batch idx
            const size_t oh = (size_t)row * HDIM + col;
            const float hold = (float)A.h_in_hi[oh] + (float)A.h_in_lo[oh];
            const float r = sigm_f(sr[i] + bir + bhr);
            const float z = sigm_f(sz[i] + biz + bhz);
            const float n = tanh_f((sin_[i] + bin) + r * (shn[i] + bhn));
            const float hnew = (1.0f - z) * n + z * hold;
            const bool msk = A.t < lengths[row];
            const float hnext = msk ? hnew : hold;
            const bf16_t hb = (bf16_t)hnext;
            A.h_out_hi[oh] = hb;
            A.h_out_lo[oh] = (bf16_t)(hnext - (float)hb);
            const float yv = msk ? hnew : 0.0f;
            if (A.y_bf)  A.y_bf[oh]  = (bf16_t)yv;
            if (A.y_f32) A.y_f32[oh] = yv;
            if (A.h_final) A.h_final[oh] = hnext;
        }
    }
}

extern "C" void kernel_launch(void* const* d_in, const int* in_sizes, int n_in,
                              void* d_out, int out_size, void* d_ws, size_t ws_size,
                              hipStream_t stream) {
    const float* x         = (const float*)d_in[0];
    const float* hidden    = (const float*)d_in[1];
    const float* w_ih0     = (const float*)d_in[2];
    const float* w_ih_rest = (const float*)d_in[3];
    const float* w_hh      = (const float*)d_in[4];
    const float* b_ih      = (const float*)d_in[5];
    const float* b_hh      = (const float*)d_in[6];
    const int*   lengths   = (const int*)d_in[8];

    float* ys   = (float*)d_out;               // (T, B, H) fp32 — last layer only
    float* hfin = ys + (size_t)T_STEPS * BH;   // (L, B, H) fp32

    // Workspace (~108 MB): bf16 weights (47.2), per-layer h hi/lo ping-pong
    // (4 MB), x in bf16 (32 MB), inter-layer bf16 rings (3 x 8 MB).
    char* ws = (char*)d_ws;
    bf16_t* wb_ih0  = (bf16_t*)ws;                                   // 3072*512
    bf16_t* wb_rest = wb_ih0 + (size_t)G3 * IDIM;                    // 3*3072*1024
    bf16_t* wb_hh   = wb_rest + (size_t)(NLAYERS - 1) * G3 * HDIM;   // 4*3072*1024
    bf16_t* hbase   = wb_hh + (size_t)NLAYERS * G3 * HDIM;           // 4 layers * 4*BH
    bf16_t* xb      = hbase + (size_t)NLAYERS * 4 * BH;              // T*B*IDIM
    bf16_t* ybuf    = xb + (size_t)T_STEPS * BATCH * IDIM;           // 3 * RING * BH

    // Convert all weights + x fp32 -> bf16 once.
    {
        int n4;
        n4 = G3 * IDIM / 4;
        cvt_f2b<<<(n4 + 255) / 256, 256, 0, stream>>>(w_ih0, wb_ih0, n4);
        n4 = (NLAYERS - 1) * G3 * HDIM / 4;
        cvt_f2b<<<(n4 + 255) / 256, 256, 0, stream>>>(w_ih_rest, wb_rest, n4);
        n4 = NLAYERS * G3 * HDIM / 4;
        cvt_f2b<<<(n4 + 255) / 256, 256, 0, stream>>>(w_hh, wb_hh, n4);
        n4 = T_STEPS * BATCH * IDIM / 4;
        cvt_f2b<<<(n4 + 255) / 256, 256, 0, stream>>>(x, xb, n4);
    }

    // Seed every layer's h ping-pong slot 0 with its initial hidden state.
    for (int l = 0; l < NLAYERS; ++l) {
        bf16_t* hb = hbase + (size_t)l * 4 * BH;
        split_h<<<BH / 4 / 256, 256, 0, stream>>>(hidden + (size_t)l * BH, hb, hb + BH);
    }

    const int nch = T_STEPS / CHUNK;

    // Wavefront over chunks: iteration s advances (layer l, chunk c=s-l) for
    // all valid l in one fused launch per timestep. Layer l at time t reads
    // layer l-1's output from ring slot (t & RING-1), written in iteration
    // s-1; within an iteration, layer l-1 writes slots (t+CHUNK) & RING-1 —
    // disjoint, so no intra-launch race.
    for (int s = 0; s < nch + NLAYERS - 1; ++s) {
        for (int tt = 0; tt < CHUNK; ++tt) {
            StepArgs sa;
            int na = 0;
            for (int l = 0; l < NLAYERS; ++l) {
                const int c = s - l;
                if (c < 0 || c >= nch) continue;
                const int t = c * CHUNK + tt;
                const bool rd0 = ((t & 1) == 0);
                bf16_t* hb = hbase + (size_t)l * 4 * BH;
                bf16_t* hhi0 = hb, *hlo0 = hb + BH, *hhi1 = hb + 2 * BH, *hlo1 = hb + 3 * BH;
                LayerStep& P = sa.L[na++];
                if (l == 0) {
                    P.inp = xb + (size_t)t * BATCH * IDIM;
                    P.kin = IDIM;
                    P.w_ih = wb_ih0;
                } else {
                    P.inp = ybuf + (size_t)(l - 1) * RING * BH
                                 + (size_t)(t & (RING - 1)) * BH;
                    P.kin = HDIM;
                    P.w_ih = wb_rest + (size_t)(l - 1) * G3 * HDIM;
                }
                P.w_hh     = wb_hh + (size_t)l * G3 * HDIM;
                P.b_ih     = b_ih + (size_t)l * G3;
                P.b_hh     = b_hh + (size_t)l * G3;
                P.h_in_hi  = rd0 ? hhi0 : hhi1;
                P.h_in_lo  = rd0 ? hlo0 : hlo1;
                P.h_out_hi = rd0 ? hhi1 : hhi0;
                P.h_out_lo = rd0 ? hlo1 : hlo0;
                P.y_bf     = (l < NLAYERS - 1)
                           ? (ybuf + (size_t)l * RING * BH + (size_t)(t & (RING - 1)) * BH)
                           : nullptr;
                P.y_f32    = (l == NLAYERS - 1) ? (ys + (size_t)t * BH) : nullptr;
                P.h_final  = (t == T_STEPS - 1) ? (hfin + (size_t)l * BH) : nullptr;
                P.t        = t;
            }
            dim3 gridB(HDIM / 16, BATCH / 64, na);
            gru_step_multi<<<gridB, 512, 0, stream>>>(sa, lengths);
        }
    }
}